// Round 1
// baseline (755.536 us; speedup 1.0000x reference)
//
#include <hip/hip_runtime.h>

// WaterNetModel: sequential scan over NT timesteps; NS sites x NH buckets.
// Outputs (concatenated in d_out): Q [NT,NS], H [NT,NS,NH], S [NT,NS,NH], fp32.
// Thread layout: one thread per (site, hidden); hidden is the fastest index so
// H/S stores are fully coalesced (consecutive lanes -> consecutive dwords).

constexpr int NT = 1096;
constexpr int NS = 2048;
constexpr int NH = 16;

__global__ __launch_bounds__(64) void waternet_kernel(
    const float* __restrict__ P, const float* __restrict__ T,
    const float* __restrict__ w_i, const float* __restrict__ w_o,
    const float* __restrict__ w_l, const float* __restrict__ w_s,
    float* __restrict__ Q, float* __restrict__ H, float* __restrict__ S)
{
    const int gid  = blockIdx.x * 64 + (int)threadIdx.x;  // 0 .. NS*NH-1
    const int hh   = gid & (NH - 1);
    const int site = gid >> 4;

    // Time-invariant per-hidden gate factors
    const float melt_coef = expf(w_s[hh]) + 1.0f;
    const float gi = 1.0f / (1.0f + expf(-w_i[hh]));
    const float gl = 1.0f / (1.0f + expf(-w_l[hh]));
    float mx = -1e30f;
    #pragma unroll
    for (int j = 0; j < NH; ++j) mx = fmaxf(mx, w_o[j]);
    float denom = 0.0f;
    #pragma unroll
    for (int j = 0; j < NH; ++j) denom += expf(w_o[j] - mx);
    const float a = expf(w_o[hh] - mx) / denom;

    float s = 0.0f, h = 0.0f;
    const float* Pp = P + site;
    const float* Tp = T + site;

    // Software pipeline: prefetch P/T one step ahead.
    float Pk = Pp[0];
    float Tk = Tp[0];

    for (int t = 0; t < NT; ++t) {
        float Pn = 0.0f, Tn = 0.0f;
        if (t + 1 < NT) {
            Pn = Pp[(t + 1) * NS];
            Tn = Tp[(t + 1) * NS];
        }

        // SnowBucket (nm=0)
        const float sm = fmaxf(Tk, 0.0f) * melt_coef;   // potential melt
        const float m  = fminf(sm, s);                  // actual melt
        s = s - m + ((Tk < 0.0f) ? Pk : 0.0f);          // snow store update
        // input gate + LinearBucket
        const float xin = (((Tk > 0.0f) ? Pk : 0.0f) + m) * gi;
        const float q   = (xin + h) * gl;
        h = h - q + xin;

        const int ofs = t * (NS * NH) + gid;            // < 2^26, int is safe
        S[ofs] = s;
        H[ofs] = h;

        // Q_k = sum_h q*a over the 16-lane hidden group (butterfly reduce)
        float qa = q * a;
        qa += __shfl_xor(qa, 1, 16);
        qa += __shfl_xor(qa, 2, 16);
        qa += __shfl_xor(qa, 4, 16);
        qa += __shfl_xor(qa, 8, 16);
        if (hh == 0) Q[t * NS + site] = qa;

        Pk = Pn; Tk = Tn;
    }
}

extern "C" void kernel_launch(void* const* d_in, const int* in_sizes, int n_in,
                              void* d_out, int out_size, void* d_ws, size_t ws_size,
                              hipStream_t stream) {
    const float* P   = (const float*)d_in[0];
    const float* T   = (const float*)d_in[1];
    const float* w_i = (const float*)d_in[2];
    const float* w_o = (const float*)d_in[3];
    const float* w_l = (const float*)d_in[4];
    const float* w_s = (const float*)d_in[5];

    float* Q = (float*)d_out;
    float* H = Q + (size_t)NT * NS;
    float* S = H + (size_t)NT * NS * NH;

    waternet_kernel<<<(NS * NH) / 64, 64, 0, stream>>>(P, T, w_i, w_o, w_l, w_s, Q, H, S);
}